// Round 8
// baseline (128.572 us; speedup 1.0000x reference)
//
#include <hip/hip_runtime.h>

#define NUM_FRAME 300
#define LEN_FRAME 512
#define T_LEN     20000

typedef float floatx4 __attribute__((ext_vector_type(4)));
typedef int   intx8   __attribute__((ext_vector_type(8)));
typedef int   int2a   __attribute__((ext_vector_type(2), aligned(4)));
typedef int   int2w   __attribute__((ext_vector_type(2)));   // 8B-aligned -> ds_write_b64
typedef unsigned int uint32;

// Per-pair LDS layout (BYTES), fp8 e4m3 samples (scaled x32). ext a8[x]=a[x&511].
//
// k-slot bijection (both operands): MFMA slot (q,t,r) -> k = 8q + 32t + r + 128u.
//
// A image [0,768): ext x in [272,1036) at byte x-272 (12B periodic tail at
//   [752,764) = a8[0..11]).  DOUBLES as B shift-image s=0 (B_s0[p] = a8[p]
//   read at byte p+240 = ext p+512).
//   A-operand reads (read2_b32, dword d = 60 + 2q - 4il + 8t + 32u): every
//   bank gets 4 lanes = 2 broadcast pairs ((il,q)==(il+1,q+2) same address)
//   = 2 distinct addr/bank -> free for b32 (R5-verified broadcast class).
//   R2/R6 lesson: b64/b128 lane-pairs do NOT broadcast-coalesce -> b32 only.
// B images s=1..3 at 240+536s: b_s[p]=a8[(p+s)&511], p in [0,528).
//   Read dword = 28 + 6s + h + 2q + 8t (mod 32), s=0..3 INCLUDING the shared
//   s=0 image -> exactly R5's measured-free B bank family (720K ~= noise).
#define B_STR  536
#define PAIR8  2376           // 240+536*4 + 232 tail span; 8 pairs = 19008 B -> 8 blocks/CU

// Compile-time Hann*32 window table: w[n] = 32 * sin^2(pi*n/512) (Taylor, ~1e-16).
struct alignas(16) WinTab {
    float w[512];
    constexpr WinTab() : w{} {
        for (int n = 0; n < 512; ++n) {
            int mm = (n <= 256) ? n : 512 - n;
            double x = 3.14159265358979323846 * (double)mm / 512.0;
            double t = x, s = x, x2 = x * x;
            for (int i = 1; i <= 10; ++i) { t *= -x2 / (double)((2 * i) * (2 * i + 1)); s += t; }
            w[n] = (float)(32.0 * s * s);
        }
    }
};
__device__ const WinTab wtab{};

__global__ __launch_bounds__(256, 8) void acorr_fp8(const float* __restrict__ in,
                                                    float* __restrict__ out) {
    __shared__ __align__(16) char lds8[8 * PAIR8];   // 19008 B

    const int tid = threadIdx.x;
    const int fj  = tid >> 6;          // frame within block (wave fj computes frame fj)
    const int m   = tid & 63;          // owns samples x0..x0+7
    const int x0  = 8 * m;

    // ---------------- staging: window (table) -> fp8(x32) -> A image + 3 B shift-images ----------------
    {
        const int G  = blockIdx.x * 4 + fj;
        const int bc = (int)((unsigned)G / (unsigned)NUM_FRAME);
        const int fr = G - bc * NUM_FRAME;
        // exact: floor(fr*19488/299); fr=299 -> exactly 19488 (matches f64 linspace).
        const int start = (int)(((unsigned)fr * (unsigned)(T_LEN - LEN_FRAME))
                                / (unsigned)(NUM_FRAME - 1));
        const float2* src = (const float2*)(in + (size_t)2 * ((size_t)bc * T_LEN + start));

        const int cn = (x0 + 8) & 511;                 // circular context base (3 bytes used)

        const float2 v0 = src[x0],     v1 = src[x0 + 1], v2 = src[x0 + 2], v3 = src[x0 + 3];
        const float2 v4 = src[x0 + 4], v5 = src[x0 + 5], v6 = src[x0 + 6], v7 = src[x0 + 7];
        const float2 c0 = src[cn],     c1 = src[cn + 1], c2 = src[cn + 2], c3 = src[cn + 3];

        const floatx4 wva = *(const floatx4*)&wtab.w[x0];
        const floatx4 wvb = *(const floatx4*)&wtab.w[x0 + 4];
        const floatx4 wvc = *(const floatx4*)&wtab.w[cn];

        #pragma unroll
        for (int c = 0; c < 2; ++c) {
            float f0 = (c ? v0.y : v0.x) * wva[0];
            float f1 = (c ? v1.y : v1.x) * wva[1];
            float f2 = (c ? v2.y : v2.x) * wva[2];
            float f3 = (c ? v3.y : v3.x) * wva[3];
            float f4 = (c ? v4.y : v4.x) * wvb[0];
            float f5 = (c ? v5.y : v5.x) * wvb[1];
            float f6 = (c ? v6.y : v6.x) * wvb[2];
            float f7 = (c ? v7.y : v7.x) * wvb[3];
            float g0 = (c ? c0.y : c0.x) * wvc[0];
            float g1 = (c ? c1.y : c1.x) * wvc[1];
            float g2 = (c ? c2.y : c2.x) * wvc[2];
            float g3 = (c ? c3.y : c3.x) * wvc[3];

            int d0 = __builtin_amdgcn_cvt_pk_fp8_f32(f0, f1, 0,  false);
            d0     = __builtin_amdgcn_cvt_pk_fp8_f32(f2, f3, d0, true);
            int d1 = __builtin_amdgcn_cvt_pk_fp8_f32(f4, f5, 0,  false);
            d1     = __builtin_amdgcn_cvt_pk_fp8_f32(f6, f7, d1, true);
            int d2 = __builtin_amdgcn_cvt_pk_fp8_f32(g0, g1, 0,  false);
            d2     = __builtin_amdgcn_cvt_pk_fp8_f32(g2, g3, d2, true);

            char* P = &lds8[(fj * 2 + c) * PAIR8];
            // A image (= B image s=0): ext [272,1036) at byte x-272
            *(int2w*)(P + 240 + x0) = (int2w){d0, d1};            // ext [512,1024)
            if (x0 >= 272)
                *(int2w*)(P + x0 - 272) = (int2w){d0, d1};        // ext [272,512)
            if (x0 < 16)
                *(int2w*)(P + 752 + x0) = (int2w){d0, d1};        // ext [1024,1040) tail (12B used)
            #pragma unroll
            for (int s = 1; s < 4; ++s) {
                int e0 = (int)__builtin_amdgcn_alignbyte((uint32)d1, (uint32)d0, (uint32)s);
                int e1 = (int)__builtin_amdgcn_alignbyte((uint32)d2, (uint32)d1, (uint32)s);
                *(int2w*)(P + 240 + B_STR * s + x0) = (int2w){e0, e1};
                if (x0 < 16)                                       // periodic tail [512,528)
                    *(int2w*)(P + 240 + B_STR * s + x0 + 512) = (int2w){e0, e1};
            }
        }
    }
    __syncthreads();

    // ---------------- MFMA main: wave = frame; both channels; 4 x (16x16x128 f8f6f4 fp8) ----------------
    const int lane = tid & 63;
    const int il   = lane & 15;    // A row i / B col j
    const int q    = lane >> 4;

    const char* P0 = &lds8[(fj * 2) * PAIR8];                     // ch0; ch1 at +PAIR8
    // A row il slot-chunk: ext 512 - 16il + 8q + 32t + 128u -> byte 240 + 8q - 16il (+...).
    const char* aP = P0 + 240 + 8 * q - 16 * il;
    // B col j = s + 4h: image_s[8q + 4h + 32t + 128u]; base_s = 240 + 536s (s=0 -> A image).
    const char* bP = P0 + 240 + B_STR * (il & 3) + 4 * (il >> 2) + 8 * q;

    floatx4 acc0 = {0.f, 0.f, 0.f, 0.f};
    floatx4 acc1 = {0.f, 0.f, 0.f, 0.f};
    #pragma unroll
    for (int u = 0; u < 4; ++u) {
        const int o = 128 * u;
        // ch0
        {
            int2a a0 = *(const int2a*)(aP + o);                   // ds_read2_b32 x4 (broadcast-free)
            int2a a1 = *(const int2a*)(aP + o + 32);
            int2a a2 = *(const int2a*)(aP + o + 64);
            int2a a3 = *(const int2a*)(aP + o + 96);
            int2a b0 = *(const int2a*)(bP + o);                   // ds_read2_b32 x4
            int2a b1 = *(const int2a*)(bP + o + 32);
            int2a b2 = *(const int2a*)(bP + o + 64);
            int2a b3 = *(const int2a*)(bP + o + 96);
            intx8 a = {a0.x, a0.y, a1.x, a1.y, a2.x, a2.y, a3.x, a3.y};
            intx8 b = {b0.x, b0.y, b1.x, b1.y, b2.x, b2.y, b3.x, b3.y};
            acc0 = __builtin_amdgcn_mfma_scale_f32_16x16x128_f8f6f4(
                a, b, acc0, 0, 0, 0, 0x7F7F7F7F, 0, 0x7F7F7F7F);  // scales = 1.0 (e8m0 127)
        }
        // ch1
        {
            int2a a0 = *(const int2a*)(aP + PAIR8 + o);
            int2a a1 = *(const int2a*)(aP + PAIR8 + o + 32);
            int2a a2 = *(const int2a*)(aP + PAIR8 + o + 64);
            int2a a3 = *(const int2a*)(aP + PAIR8 + o + 96);
            int2a b0 = *(const int2a*)(bP + PAIR8 + o);
            int2a b1 = *(const int2a*)(bP + PAIR8 + o + 32);
            int2a b2 = *(const int2a*)(bP + PAIR8 + o + 64);
            int2a b3 = *(const int2a*)(bP + PAIR8 + o + 96);
            intx8 a = {a0.x, a0.y, a1.x, a1.y, a2.x, a2.y, a3.x, a3.y};
            intx8 b = {b0.x, b0.y, b1.x, b1.y, b2.x, b2.y, b3.x, b3.y};
            acc1 = __builtin_amdgcn_mfma_scale_f32_16x16x128_f8f6f4(
                a, b, acc1, 0, 0, 0, 0x7F7F7F7F, 0, 0x7F7F7F7F);
        }
    }

    // ---------------- epilogue: per-channel relu + 1/sqrt(acf0), in-register mean, store ----------------
    // C/D layout: col j = lane&15, row i = 4q + reg -> lag = 16i + j. acc = 1024*acf.
    float n00 = __int_as_float(__builtin_amdgcn_readfirstlane(__float_as_int(acc0[0])));
    float n01 = __int_as_float(__builtin_amdgcn_readfirstlane(__float_as_int(acc1[0])));
    float n0r0 = fmaxf(n00, 0.f);
    float n0r1 = fmaxf(n01, 0.f);
    float inv0 = (n0r0 == 0.f) ? (1.0f / 1024.0f) : (rsqrtf(n0r0) * (1.0f / 32.0f));
    float inv1 = (n0r1 == 0.f) ? (1.0f / 1024.0f) : (rsqrtf(n0r1) * (1.0f / 32.0f));

    const int G = blockIdx.x * 4 + fj;
    float* ob = out + (size_t)G * 256 + q * 64 + il;
    ob[ 0] = 0.5f * (fmaxf(acc0[0], 0.f) * inv0 + fmaxf(acc1[0], 0.f) * inv1);
    ob[16] = 0.5f * (fmaxf(acc0[1], 0.f) * inv0 + fmaxf(acc1[1], 0.f) * inv1);
    ob[32] = 0.5f * (fmaxf(acc0[2], 0.f) * inv0 + fmaxf(acc1[2], 0.f) * inv1);
    ob[48] = 0.5f * (fmaxf(acc0[3], 0.f) * inv0 + fmaxf(acc1[3], 0.f) * inv1);
}

extern "C" void kernel_launch(void* const* d_in, const int* in_sizes, int n_in,
                              void* d_out, int out_size, void* d_ws, size_t ws_size,
                              hipStream_t stream) {
    const float* in = (const float*)d_in[0];
    float* out = (float*)d_out;
    dim3 grid(15000);    // 60000 frames / 4 per block (1 wave per frame, both channels)
    dim3 block(256);
    acorr_fp8<<<grid, block, 0, stream>>>(in, out);
}

// Round 9
// 118.822 us; speedup vs baseline: 1.0821x; 1.0821x over previous
//
#include <hip/hip_runtime.h>

#define NUM_FRAME 300
#define LEN_FRAME 512
#define T_LEN     20000

typedef float floatx4 __attribute__((ext_vector_type(4)));
typedef int   intx8   __attribute__((ext_vector_type(8)));
typedef int   int2a   __attribute__((ext_vector_type(2), aligned(4)));
typedef int   int2w   __attribute__((ext_vector_type(2)));   // 8B-aligned -> ds_write_b64
typedef unsigned int uint32;

// Per-pair LDS layout (BYTES), fp8 e4m3 samples (scaled x32). ext a8[x]=a[x&511].
//
// k-slot bijection (both operands): MFMA slot (q,t,r) -> k = 8q + 32t + r + 128u.
//
// EMPIRICAL LDS LAW (R2/R3/R5/R6/R8): conflict cost = lanes-per-bank, with NO
// same-address broadcast coalescing; <=2 lanes/bank free. Only the parity-split
// read2_b32 A scheme (A0 even dwords for il<8, A1 copy at +4 mod 8 -> odd
// dwords for il>=8; 2 lanes/bank) measures free. Wide reads (b64/b128) and
// single-image A (4 lanes/bank even-only) each cost +512 cyc/block.
//
//  A0 [0,768):     ext x in [272,1040) at byte x-272.  il<8 A-reads (even
//                  dwords, 2 lanes/bank) AND B shift-image s=0 (B_s0[p]=a8[p]
//                  at byte p+240; dword-granular -> R8-verified free).
//  A1 [772,1524):  ext x in [272,1024) at byte 772+(x-272); 772 == 4 mod 8 ->
//                  il>=8 A-reads hit odd dwords, 2 lanes/bank (R5-verified).
//  B s=1..3 at 1008+536s = 1544/2080/2616, span 528 each: b_s[p]=a8[(p+s)&511].
//                  Bases == 112+24s mod 128 -> read dword residue 28+6s+h+2q+8t,
//                  the R5/R8-measured-free B bank family.
#define PAIR8  3152           // 16-aligned; 8 pairs = 25216 B -> 6 blocks/CU

// Compile-time Hann*32 window table: w[n] = 32 * sin^2(pi*n/512) (Taylor, ~1e-16).
struct alignas(16) WinTab {
    float w[512];
    constexpr WinTab() : w{} {
        for (int n = 0; n < 512; ++n) {
            int mm = (n <= 256) ? n : 512 - n;
            double x = 3.14159265358979323846 * (double)mm / 512.0;
            double t = x, s = x, x2 = x * x;
            for (int i = 1; i <= 10; ++i) { t *= -x2 / (double)((2 * i) * (2 * i + 1)); s += t; }
            w[n] = (float)(32.0 * s * s);
        }
    }
};
__device__ const WinTab wtab{};

__global__ __launch_bounds__(256, 6) void acorr_fp8(const float* __restrict__ in,
                                                    float* __restrict__ out) {
    __shared__ __align__(16) char lds8[8 * PAIR8];   // 25216 B

    const int tid = threadIdx.x;
    const int fj  = tid >> 6;          // frame within block (wave fj computes frame fj)
    const int m   = tid & 63;          // owns samples x0..x0+7
    const int x0  = 8 * m;

    // ---------------- staging: window (table) -> fp8(x32) -> A0(+s=0)/A1 + 3 B shift-images ----------------
    {
        const int G  = blockIdx.x * 4 + fj;
        const int bc = (int)((unsigned)G / (unsigned)NUM_FRAME);
        const int fr = G - bc * NUM_FRAME;
        // exact: floor(fr*19488/299); fr=299 -> exactly 19488 (matches f64 linspace).
        const int start = (int)(((unsigned)fr * (unsigned)(T_LEN - LEN_FRAME))
                                / (unsigned)(NUM_FRAME - 1));
        const float2* src = (const float2*)(in + (size_t)2 * ((size_t)bc * T_LEN + start));

        const int cn = (x0 + 8) & 511;                 // circular context base (3 bytes used)

        const float2 v0 = src[x0],     v1 = src[x0 + 1], v2 = src[x0 + 2], v3 = src[x0 + 3];
        const float2 v4 = src[x0 + 4], v5 = src[x0 + 5], v6 = src[x0 + 6], v7 = src[x0 + 7];
        const float2 c0 = src[cn],     c1 = src[cn + 1], c2 = src[cn + 2], c3 = src[cn + 3];

        const floatx4 wva = *(const floatx4*)&wtab.w[x0];
        const floatx4 wvb = *(const floatx4*)&wtab.w[x0 + 4];
        const floatx4 wvc = *(const floatx4*)&wtab.w[cn];

        #pragma unroll
        for (int c = 0; c < 2; ++c) {
            float f0 = (c ? v0.y : v0.x) * wva[0];
            float f1 = (c ? v1.y : v1.x) * wva[1];
            float f2 = (c ? v2.y : v2.x) * wva[2];
            float f3 = (c ? v3.y : v3.x) * wva[3];
            float f4 = (c ? v4.y : v4.x) * wvb[0];
            float f5 = (c ? v5.y : v5.x) * wvb[1];
            float f6 = (c ? v6.y : v6.x) * wvb[2];
            float f7 = (c ? v7.y : v7.x) * wvb[3];
            float g0 = (c ? c0.y : c0.x) * wvc[0];
            float g1 = (c ? c1.y : c1.x) * wvc[1];
            float g2 = (c ? c2.y : c2.x) * wvc[2];
            float g3 = (c ? c3.y : c3.x) * wvc[3];

            int d0 = __builtin_amdgcn_cvt_pk_fp8_f32(f0, f1, 0,  false);
            d0     = __builtin_amdgcn_cvt_pk_fp8_f32(f2, f3, d0, true);
            int d1 = __builtin_amdgcn_cvt_pk_fp8_f32(f4, f5, 0,  false);
            d1     = __builtin_amdgcn_cvt_pk_fp8_f32(f6, f7, d1, true);
            int d2 = __builtin_amdgcn_cvt_pk_fp8_f32(g0, g1, 0,  false);
            d2     = __builtin_amdgcn_cvt_pk_fp8_f32(g2, g3, d2, true);

            char* P = &lds8[(fj * 2 + c) * PAIR8];
            // A0 (= B image s=0): ext [272,1040) at byte x-272
            *(int2w*)(P + 240 + x0) = (int2w){d0, d1};            // ext [512,1024)
            if (x0 >= 272)
                *(int2w*)(P + x0 - 272) = (int2w){d0, d1};        // ext [272,512)
            if (x0 < 16)
                *(int2w*)(P + 752 + x0) = (int2w){d0, d1};        // ext [1024,1040) tail
            // A1 parity copy: ext [272,1024) at byte 772+(x-272)  (772 == 4 mod 8)
            *(int2a*)(P + 1012 + x0) = (int2a){d0, d1};           // ext [512,1024)
            if (x0 >= 272)
                *(int2a*)(P + 500 + x0) = (int2a){d0, d1};        // ext [272,512)
            // B shift-images s=1..3
            #pragma unroll
            for (int s = 1; s < 4; ++s) {
                int e0 = (int)__builtin_amdgcn_alignbyte((uint32)d1, (uint32)d0, (uint32)s);
                int e1 = (int)__builtin_amdgcn_alignbyte((uint32)d2, (uint32)d1, (uint32)s);
                char* Bp = P + 1008 + 536 * s;
                *(int2w*)(Bp + x0) = (int2w){e0, e1};
                if (x0 < 16)                                       // periodic tail [512,528)
                    *(int2w*)(Bp + x0 + 512) = (int2w){e0, e1};
            }
        }
    }
    __syncthreads();

    // ---------------- MFMA main: wave = frame; both channels; 4 x (16x16x128 f8f6f4 fp8) ----------------
    const int lane = tid & 63;
    const int il   = lane & 15;    // A row i / B col j
    const int q    = lane >> 4;

    const char* P0 = &lds8[(fj * 2) * PAIR8];                     // ch0; ch1 at +PAIR8
    // A row il slot-chunk: ext 512 - 16il + 8q + 32t + 128u.
    //   il<8 -> A0 (byte 240+...-272 base, even dwords); il>=8 -> A1 (odd dwords).
    const char* aP = P0 + (((il & 8) ? 1012 : 240) + 8 * q - 16 * il);
    // B col j = s + 4h: image_s[8q + 4h + 32t + 128u]; base_s: s=0 -> A0 image.
    const int sB = il & 3;
    const char* bP = P0 + ((sB == 0) ? 240 : (1008 + 536 * sB)) + 4 * (il >> 2) + 8 * q;

    floatx4 acc0 = {0.f, 0.f, 0.f, 0.f};
    floatx4 acc1 = {0.f, 0.f, 0.f, 0.f};
    #pragma unroll
    for (int u = 0; u < 4; ++u) {
        const int o = 128 * u;
        // ch0
        {
            int2a a0 = *(const int2a*)(aP + o);                   // ds_read2_b32 x4, parity-split
            int2a a1 = *(const int2a*)(aP + o + 32);
            int2a a2 = *(const int2a*)(aP + o + 64);
            int2a a3 = *(const int2a*)(aP + o + 96);
            int2a b0 = *(const int2a*)(bP + o);                   // ds_read2_b32 x4
            int2a b1 = *(const int2a*)(bP + o + 32);
            int2a b2 = *(const int2a*)(bP + o + 64);
            int2a b3 = *(const int2a*)(bP + o + 96);
            intx8 a = {a0.x, a0.y, a1.x, a1.y, a2.x, a2.y, a3.x, a3.y};
            intx8 b = {b0.x, b0.y, b1.x, b1.y, b2.x, b2.y, b3.x, b3.y};
            acc0 = __builtin_amdgcn_mfma_scale_f32_16x16x128_f8f6f4(
                a, b, acc0, 0, 0, 0, 0x7F7F7F7F, 0, 0x7F7F7F7F);  // scales = 1.0 (e8m0 127)
        }
        // ch1
        {
            int2a a0 = *(const int2a*)(aP + PAIR8 + o);
            int2a a1 = *(const int2a*)(aP + PAIR8 + o + 32);
            int2a a2 = *(const int2a*)(aP + PAIR8 + o + 64);
            int2a a3 = *(const int2a*)(aP + PAIR8 + o + 96);
            int2a b0 = *(const int2a*)(bP + PAIR8 + o);
            int2a b1 = *(const int2a*)(bP + PAIR8 + o + 32);
            int2a b2 = *(const int2a*)(bP + PAIR8 + o + 64);
            int2a b3 = *(const int2a*)(bP + PAIR8 + o + 96);
            intx8 a = {a0.x, a0.y, a1.x, a1.y, a2.x, a2.y, a3.x, a3.y};
            intx8 b = {b0.x, b0.y, b1.x, b1.y, b2.x, b2.y, b3.x, b3.y};
            acc1 = __builtin_amdgcn_mfma_scale_f32_16x16x128_f8f6f4(
                a, b, acc1, 0, 0, 0, 0x7F7F7F7F, 0, 0x7F7F7F7F);
        }
    }

    // ---------------- epilogue: per-channel relu + 1/sqrt(acf0), in-register mean, store ----------------
    // C/D layout: col j = lane&15, row i = 4q + reg -> lag = 16i + j. acc = 1024*acf.
    float n00 = __int_as_float(__builtin_amdgcn_readfirstlane(__float_as_int(acc0[0])));
    float n01 = __int_as_float(__builtin_amdgcn_readfirstlane(__float_as_int(acc1[0])));
    float n0r0 = fmaxf(n00, 0.f);
    float n0r1 = fmaxf(n01, 0.f);
    float inv0 = (n0r0 == 0.f) ? (1.0f / 1024.0f) : (rsqrtf(n0r0) * (1.0f / 32.0f));
    float inv1 = (n0r1 == 0.f) ? (1.0f / 1024.0f) : (rsqrtf(n0r1) * (1.0f / 32.0f));

    const int G = blockIdx.x * 4 + fj;
    float* ob = out + (size_t)G * 256 + q * 64 + il;
    ob[ 0] = 0.5f * (fmaxf(acc0[0], 0.f) * inv0 + fmaxf(acc1[0], 0.f) * inv1);
    ob[16] = 0.5f * (fmaxf(acc0[1], 0.f) * inv0 + fmaxf(acc1[1], 0.f) * inv1);
    ob[32] = 0.5f * (fmaxf(acc0[2], 0.f) * inv0 + fmaxf(acc1[2], 0.f) * inv1);
    ob[48] = 0.5f * (fmaxf(acc0[3], 0.f) * inv0 + fmaxf(acc1[3], 0.f) * inv1);
}

extern "C" void kernel_launch(void* const* d_in, const int* in_sizes, int n_in,
                              void* d_out, int out_size, void* d_ws, size_t ws_size,
                              hipStream_t stream) {
    const float* in = (const float*)d_in[0];
    float* out = (float*)d_out;
    dim3 grid(15000);    // 60000 frames / 4 per block (1 wave per frame, both channels)
    dim3 block(256);
    acorr_fp8<<<grid, block, 0, stream>>>(in, out);
}